// Round 2
// baseline (100.358 us; speedup 1.0000x reference)
//
#include <hip/hip_runtime.h>
#include <hip/hip_bf16.h>

typedef __bf16 bf16_t;
typedef bf16_t bf16x8 __attribute__((ext_vector_type(8)));
typedef float  floatx4 __attribute__((ext_vector_type(4)));

#define NROWS 65536
#define NCENT 512
#define NDIM  128
#define TROWS 64
#define TPB   2                         // tiles per block
#define NBLK  (NROWS / (TROWS * TPB))   // 512 blocks = 2 per CU

// Single fused kernel. No workspace use at all.
//   - mu (512x128 fp32, 256 KB) loaded straight into persistent B-fragment
//     VGPRs (64/lane), converted fp32->bf16 in-register; h2=0.5|mu|^2 from the
//     CONVERTED values via quad shuffles (numerics identical to prior rounds).
//   - z tile (64x128) staged fp32->bf16 into frag-major LDS:
//     elem(row,k): s=row>>4, r16=row&15, kk=k>>5, quad=(k>>3)&3, e=k&7
//     addr = s*2048 + kk*512 + quad*128 + r16*8 + e
//     Granule map g=tid (+512): global reads coalesce to 128B/row; ds_write and
//     ds_read (A-frags) are contiguous 16B/lane -> conflict-free by construction.
//   - z2 (per-row |z|^2 of rounded values) recomputed from A-frags by wave 0.

__global__ __launch_bounds__(512, 4)
void kmeans_fused(const float* __restrict__ z, const float* __restrict__ mu,
                  float* __restrict__ out)
{
    __shared__ bf16_t zt[TROWS * NDIM];   // 16 KB
    __shared__ float  z2s[TROWS];         // 256 B
    __shared__ float  rmx[8][TROWS];      // 2 KB

    const int tid  = threadIdx.x;
    const int lane = tid & 63;
    const int w    = tid >> 6;       // 8 waves; wave w owns centroids [w*64, w*64+64)
    const int quad = lane >> 4;
    const int l16  = lane & 15;

    const size_t tbase = (size_t)blockIdx.x * TPB * TROWS * NDIM;

    // ---- issue tile-0 z loads first; they fly under the mu prologue ----
    const int g0 = tid, g1 = tid + 512;
    const int o0 = ((g0 >> 8) * 16 + (g0 & 15)) * NDIM + ((g0 >> 6) & 3) * 32 + ((g0 >> 4) & 3) * 8;
    const int o1 = ((g1 >> 8) * 16 + (g1 & 15)) * NDIM + ((g1 >> 6) & 3) * 32 + ((g1 >> 4) & 3) * 8;
    float4 pa0 = *(const float4*)(z + tbase + o0);
    float4 pa1 = *(const float4*)(z + tbase + o0 + 4);
    float4 pb0 = *(const float4*)(z + tbase + o1);
    float4 pb1 = *(const float4*)(z + tbase + o1 + 4);

    // ---- persistent B fragments straight from fp32 mu (L2-shared across blocks) ----
    bf16x8 bfr[4][4];
    float  h2r[4];
#pragma unroll
    for (int g = 0; g < 4; ++g) {
        const int col = w * 64 + g * 16 + l16;
#pragma unroll
        for (int kk = 0; kk < 4; ++kk) {
            const float* mp = mu + col * NDIM + kk * 32 + quad * 8;
            const float4 a = *(const float4*)(mp);
            const float4 b = *(const float4*)(mp + 4);
            bfr[g][kk] = (bf16x8){(bf16_t)a.x, (bf16_t)a.y, (bf16_t)a.z, (bf16_t)a.w,
                                  (bf16_t)b.x, (bf16_t)b.y, (bf16_t)b.z, (bf16_t)b.w};
        }
        float ss = 0.f;
#pragma unroll
        for (int kk = 0; kk < 4; ++kk)
#pragma unroll
            for (int e = 0; e < 8; ++e) { float f = (float)bfr[g][kk][e]; ss = fmaf(f, f, ss); }
        ss += __shfl_xor(ss, 16);   // sum over the 4 quads (k-chunks) of this col
        ss += __shfl_xor(ss, 32);
        h2r[g] = 0.5f * ss;
    }

    // ---- finish tile-0 staging: cvt + contiguous ds_write ----
    {
        bf16x8 k0 = {(bf16_t)pa0.x, (bf16_t)pa0.y, (bf16_t)pa0.z, (bf16_t)pa0.w,
                     (bf16_t)pa1.x, (bf16_t)pa1.y, (bf16_t)pa1.z, (bf16_t)pa1.w};
        bf16x8 k1 = {(bf16_t)pb0.x, (bf16_t)pb0.y, (bf16_t)pb0.z, (bf16_t)pb0.w,
                     (bf16_t)pb1.x, (bf16_t)pb1.y, (bf16_t)pb1.z, (bf16_t)pb1.w};
        *(bf16x8*)&zt[g0 * 8] = k0;
        *(bf16x8*)&zt[g1 * 8] = k1;
    }
    __syncthreads();   // tile 0 resident

    float fsum = 0.f;

    for (int t = 0; t < TPB; ++t) {
        // ---- compute: 4 row strips x (4 colgroups x 4 MFMA), B fully in regs ----
#pragma unroll
        for (int s = 0; s < 4; ++s) {
            bf16x8 afr[4];
#pragma unroll
            for (int kk = 0; kk < 4; ++kk)
                afr[kk] = *(const bf16x8*)&zt[s * 2048 + kk * 512 + quad * 128 + l16 * 8];

            if (w == 0) {              // z2 of rounded z, rows s*16..s*16+15
                float ss = 0.f;
#pragma unroll
                for (int kk = 0; kk < 4; ++kk)
#pragma unroll
                    for (int e = 0; e < 8; ++e) { float f = (float)afr[kk][e]; ss = fmaf(f, f, ss); }
                ss += __shfl_xor(ss, 16);
                ss += __shfl_xor(ss, 32);
                if (lane < 16) z2s[s * 16 + lane] = ss;
            }

            float vm[4] = {-3.0e38f, -3.0e38f, -3.0e38f, -3.0e38f};
#pragma unroll
            for (int g = 0; g < 4; ++g) {
                floatx4 acc = (floatx4){0.f, 0.f, 0.f, 0.f};
#pragma unroll
                for (int kk = 0; kk < 4; ++kk)
                    acc = __builtin_amdgcn_mfma_f32_16x16x32_bf16(afr[kk], bfr[g][kk], acc, 0, 0, 0);
#pragma unroll
                for (int r = 0; r < 4; ++r)
                    vm[r] = fmaxf(vm[r], acc[r] - h2r[g]);   // deferred-sqrt: max(dot - m2/2)
            }
#pragma unroll
            for (int r = 0; r < 4; ++r) {                    // max over this wave's 16 cols
                float v = vm[r];
                v = fmaxf(v, __shfl_xor(v, 1));
                v = fmaxf(v, __shfl_xor(v, 2));
                v = fmaxf(v, __shfl_xor(v, 4));
                v = fmaxf(v, __shfl_xor(v, 8));
                if (l16 == 0) rmx[w][s * 16 + quad * 4 + r] = v;
            }
        }
        __syncthreads();   // B1: rmx/z2s visible; zt reads complete

        // ---- overlapped: stage next tile (all threads) + row epilogue (tid<64) ----
        if (t + 1 < TPB) {
            const float* zsrc = z + tbase + (size_t)(t + 1) * TROWS * NDIM;
            float4 a0 = *(const float4*)(zsrc + o0);
            float4 a1 = *(const float4*)(zsrc + o0 + 4);
            float4 b0 = *(const float4*)(zsrc + o1);
            float4 b1 = *(const float4*)(zsrc + o1 + 4);
            bf16x8 k0 = {(bf16_t)a0.x, (bf16_t)a0.y, (bf16_t)a0.z, (bf16_t)a0.w,
                         (bf16_t)a1.x, (bf16_t)a1.y, (bf16_t)a1.z, (bf16_t)a1.w};
            bf16x8 k1 = {(bf16_t)b0.x, (bf16_t)b0.y, (bf16_t)b0.z, (bf16_t)b0.w,
                         (bf16_t)b1.x, (bf16_t)b1.y, (bf16_t)b1.z, (bf16_t)b1.w};
            *(bf16x8*)&zt[g0 * 8] = k0;
            *(bf16x8*)&zt[g1 * 8] = k1;
        }
        if (tid < TROWS) {
            float m = rmx[0][tid];                           // stride-4B: conflict-free
#pragma unroll
            for (int jj = 1; jj < 8; ++jj) m = fmaxf(m, rmx[jj][tid]);
            float d2 = z2s[tid] - 2.0f * m;
            fsum += sqrtf(fmaxf(d2, 0.f));                   // one sqrt per row
        }
        __syncthreads();   // B2: zt ready for next tile; rmx/z2s consumed
    }

    // ---- wave 0 holds all row sums; reduce + one atomic per block ----
    if (w == 0) {
        float v = fsum;
#pragma unroll
        for (int off = 32; off; off >>= 1) v += __shfl_down(v, off);
        if (tid == 0) atomicAdd(out, v * (1.0f / 65536.0f));
    }
}

extern "C" void kernel_launch(void* const* d_in, const int* in_sizes, int n_in,
                              void* d_out, int out_size, void* d_ws, size_t ws_size,
                              hipStream_t stream) {
    const float* z  = (const float*)d_in[0];
    const float* mu = (const float*)d_in[1];
    float* out = (float*)d_out;
    hipMemsetAsync(out, 0, sizeof(float), stream);   // d_out is poisoned 0xAA
    kmeans_fused<<<dim3(NBLK), dim3(512), 0, stream>>>(z, mu, out);
}

// Round 3
// 94.116 us; speedup vs baseline: 1.0663x; 1.0663x over previous
//
#include <hip/hip_runtime.h>
#include <hip/hip_bf16.h>

typedef __bf16 bf16_t;
typedef bf16_t bf16x8 __attribute__((ext_vector_type(8)));
typedef bf16_t bf16x4 __attribute__((ext_vector_type(4)));
typedef float  floatx4 __attribute__((ext_vector_type(4)));

#define NROWS 65536
#define NCENT 512
#define NDIM  128
#define TROWS 64
#define TPB   2                         // tiles per block
#define NBLK  (NROWS / (TROWS * TPB))   // 512 blocks = 2 per CU

// ws layout:
//   [0, 131072)          mu bf16 frag-major: addr = j*2048 + kk*512 + quad*128 + l16*8
//                        (col = j*16+l16, k = kk*32+quad*8+e)
//   [131072, 133120)     h2 = 0.5*|mu|^2 float[512]
//   [133120, 395264)     z2 float[65536] (from bf16-rounded z)
//   [395264, 17172480)   z bf16 tile-frag-major:
//                        elem(row,k) = (row>>6)*8192 + ((row>>4)&3)*2048
//                                    + (k>>5)*512 + ((k>>3)&3)*128 + (row&15)*8 + (k&7)

__device__ __forceinline__ void gload_lds16(const bf16_t* g, bf16_t* l) {
    __builtin_amdgcn_global_load_lds(
        (const __attribute__((address_space(1))) unsigned int*)g,
        (__attribute__((address_space(3))) unsigned int*)l,
        16, 0, 0);
}

// Fused prepass: z repack (fp32->bf16 tile-frag-major) + per-row z2,
// mu repack (frag-major bf16) + h2, and d_out zeroing. One dispatch.
__global__ __launch_bounds__(256)
void prepass_kernel(const float* __restrict__ z, const float* __restrict__ mu,
                    bf16_t* __restrict__ zb, float* __restrict__ z2,
                    bf16_t* __restrict__ ws_mu, float* __restrict__ ws_h2,
                    float* __restrict__ out)
{
    const int bid = blockIdx.x;
    const int tid = threadIdx.x;
    if (bid < 2048) {
        // ---- z part: 2048 blocks x 256 thr, 2 rows per 16-thread group ----
        const int gid = bid * 256 + tid;
        const int row = gid >> 3;
        const int j   = gid & 7;            // 16-elem chunk within row
        const int k0  = j * 16;
        const float4* src = (const float4*)(z + (size_t)row * NDIM + k0);
        const float4 a = src[0], b = src[1], c = src[2], d = src[3];
        bf16x8 p0 = {(bf16_t)a.x, (bf16_t)a.y, (bf16_t)a.z, (bf16_t)a.w,
                     (bf16_t)b.x, (bf16_t)b.y, (bf16_t)b.z, (bf16_t)b.w};
        bf16x8 p1 = {(bf16_t)c.x, (bf16_t)c.y, (bf16_t)c.z, (bf16_t)c.w,
                     (bf16_t)d.x, (bf16_t)d.y, (bf16_t)d.z, (bf16_t)d.w};
        const int base = (row >> 6) * 8192 + ((row >> 4) & 3) * 2048
                       + (k0 >> 5) * 512 + ((k0 >> 3) & 3) * 128 + (row & 15) * 8;
        *(bf16x8*)(zb + base)       = p0;
        *(bf16x8*)(zb + base + 128) = p1;   // next quad (k0+8)
        float ss = 0.f;
#pragma unroll
        for (int e = 0; e < 8; ++e) {
            float f0 = (float)p0[e], f1 = (float)p1[e];
            ss = fmaf(f0, f0, ss);
            ss = fmaf(f1, f1, ss);
        }
        ss += __shfl_xor(ss, 1); ss += __shfl_xor(ss, 2); ss += __shfl_xor(ss, 4);
        if (j == 0) z2[row] = ss;
    } else {
        // ---- mu part: 64 blocks x 256 thr, 8 cols per block ----
        if (bid == 2048 && tid == 0) *out = 0.f;   // replaces the memset dispatch
        const int mb = bid - 2048;
        const int col_local = tid >> 5;
        const int j = tid & 31;             // 32 threads per col, 4 floats each
        const int col = mb * 8 + col_local;
        const float4 v = *(const float4*)(mu + col * NDIM + j * 4);
        bf16x4 pk = {(bf16_t)v.x, (bf16_t)v.y, (bf16_t)v.z, (bf16_t)v.w};
        const int k0 = j * 4;
        const int kk = k0 >> 5, quad = (k0 >> 3) & 3, e0 = k0 & 7;
        const int c = col >> 6, g = (col >> 4) & 3, c16 = col & 15;
        const int addr = c * 8192 + g * 2048 + kk * 512 + quad * 128 + c16 * 8 + e0;
        *(bf16x4*)(ws_mu + addr) = pk;
        float f0 = (float)pk[0], f1 = (float)pk[1], f2 = (float)pk[2], f3 = (float)pk[3];
        float s = f0 * f0 + f1 * f1 + f2 * f2 + f3 * f3;
        s += __shfl_xor(s, 1);  s += __shfl_xor(s, 2);  s += __shfl_xor(s, 4);
        s += __shfl_xor(s, 8);  s += __shfl_xor(s, 16);
        if (j == 0) ws_h2[col] = 0.5f * s;
    }
}

// main: mu fully in VGPRs (64/lane, no spills: ~104 VGPR by construction),
// z staged via global_load_lds (bf16, frag-major), double-buffered LDS.
__global__ __launch_bounds__(512, 4)
void kmeans_main(const bf16_t* __restrict__ zb, const float* __restrict__ z2g,
                 const bf16_t* __restrict__ wmu, const float* __restrict__ wh2,
                 float* __restrict__ out)
{
    __shared__ bf16_t zt[2][TROWS * NDIM];   // 2 x 16 KB
    __shared__ float  rmx[8][TROWS];         // 2 KB  -> 34.8 KB total

    const int tid  = threadIdx.x;
    const int lane = tid & 63;
    const int w    = tid >> 6;       // 8 waves; wave w owns centroids [w*64, w*64+64)
    const int quad = lane >> 4;
    const int l16  = lane & 15;

    // ---- persistent B fragments: 4 colgroups x 4 k-chunks = 64 VGPRs/lane ----
    bf16x8 bfr[4][4];
    float  h2r[4];
#pragma unroll
    for (int g = 0; g < 4; ++g) {
        const int j = w * 4 + g;
#pragma unroll
        for (int kk = 0; kk < 4; ++kk)
            bfr[g][kk] = *(const bf16x8*)(wmu + j * 2048 + kk * 512 + quad * 128 + l16 * 8);
        h2r[g] = wh2[j * 16 + l16];
    }

    const int t0 = blockIdx.x * TPB;

    // ---- stage tile 0 (async DMA; frag-major layout is linear in LDS) ----
    {
        const bf16_t* src = zb + (size_t)t0 * (TROWS * NDIM);
#pragma unroll
        for (int i = 0; i < 2; ++i) {
            const int idx = i * 512 + tid;         // 16B units, 1024 per tile
            gload_lds16(src + idx * 8, &zt[0][idx * 8]);
        }
    }

    float fsum = 0.f;
    __syncthreads();   // B0: drains tile-0 DMA

    for (int t = 0; t < TPB; ++t) {
        const int cur = t & 1;

        // issue next-tile staging first; flies under the whole MFMA phase
        if (t + 1 < TPB) {
            const bf16_t* src = zb + (size_t)(t0 + t + 1) * (TROWS * NDIM);
#pragma unroll
            for (int i = 0; i < 2; ++i) {
                const int idx = i * 512 + tid;
                gload_lds16(src + idx * 8, &zt[cur ^ 1][idx * 8]);
            }
        }
        const float z2v = z2g[(t0 + t) * TROWS + lane];   // 1 VGPR; used by wave 0

        // ---- compute: 4 row strips x (4 colgroups x 4 MFMA); A-frags are the
        //      only LDS reads (16 ds_read_b128 per wave per tile, 4:1 MFMA:ds) ----
#pragma unroll
        for (int s = 0; s < 4; ++s) {
            bf16x8 afr[4];
#pragma unroll
            for (int kk = 0; kk < 4; ++kk)
                afr[kk] = *(const bf16x8*)&zt[cur][s * 2048 + kk * 512 + quad * 128 + l16 * 8];
            float vm[4] = {-3.0e38f, -3.0e38f, -3.0e38f, -3.0e38f};
#pragma unroll
            for (int g = 0; g < 4; ++g) {
                floatx4 acc = (floatx4){0.f, 0.f, 0.f, 0.f};
#pragma unroll
                for (int kk = 0; kk < 4; ++kk)
                    acc = __builtin_amdgcn_mfma_f32_16x16x32_bf16(afr[kk], bfr[g][kk], acc, 0, 0, 0);
#pragma unroll
                for (int r = 0; r < 4; ++r)
                    vm[r] = fmaxf(vm[r], acc[r] - h2r[g]);   // deferred-sqrt: max(dot - m2/2)
            }
#pragma unroll
            for (int r = 0; r < 4; ++r) {                    // max over this wave's 16 cols
                float v = vm[r];
                v = fmaxf(v, __shfl_xor(v, 1));
                v = fmaxf(v, __shfl_xor(v, 2));
                v = fmaxf(v, __shfl_xor(v, 4));
                v = fmaxf(v, __shfl_xor(v, 8));
                if (l16 == 0) rmx[w][s * 16 + quad * 4 + r] = v;
            }
        }
        __syncthreads();   // B1: rmx visible; next-tile DMA drained

        if (tid < TROWS) {
            float m = rmx[0][tid];                           // stride-4B: conflict-free
#pragma unroll
            for (int jj = 1; jj < 8; ++jj) m = fmaxf(m, rmx[jj][tid]);
            float d2 = z2v - 2.0f * m;                       // lane==tid for wave 0
            fsum += sqrtf(fmaxf(d2, 0.f));                   // one sqrt per row
        }
        __syncthreads();   // B2: protect rmx for next tile
    }

    // ---- wave 0 holds all row sums; reduce + one atomic per block ----
    if (w == 0) {
        float v = fsum;
#pragma unroll
        for (int off = 32; off; off >>= 1) v += __shfl_down(v, off);
        if (tid == 0) atomicAdd(out, v * (1.0f / 65536.0f));
    }
}

extern "C" void kernel_launch(void* const* d_in, const int* in_sizes, int n_in,
                              void* d_out, int out_size, void* d_ws, size_t ws_size,
                              hipStream_t stream) {
    const float* z  = (const float*)d_in[0];
    const float* mu = (const float*)d_in[1];
    float* out = (float*)d_out;
    bf16_t* ws_mu = (bf16_t*)d_ws;
    float*  ws_h2 = (float*)((char*)d_ws + 131072);
    float*  ws_z2 = (float*)((char*)d_ws + 133120);
    bf16_t* ws_zb = (bf16_t*)((char*)d_ws + 395264);
    prepass_kernel<<<dim3(2112), dim3(256), 0, stream>>>(z, mu, ws_zb, ws_z2, ws_mu, ws_h2, out);
    kmeans_main   <<<dim3(NBLK), dim3(512), 0, stream>>>(ws_zb, ws_z2, ws_mu, ws_h2, out);
}